// Round 8
// baseline (1237.563 us; speedup 1.0000x reference)
//
#include <hip/hip_runtime.h>
#include <hip/hip_fp16.h>

typedef unsigned short u16;
typedef short bf16x8 __attribute__((ext_vector_type(8)));
typedef _Float16 half8 __attribute__((ext_vector_type(8)));
typedef float f32x4 __attribute__((ext_vector_type(4)));

__device__ __forceinline__ u16 f2bf(float f) {
    unsigned u = __float_as_uint(f);
    return (u16)((u + 0x7fffu + ((u >> 16) & 1u)) >> 16);
}
__device__ __forceinline__ u16 f2h(float f) {
    __half h = __float2half_rn(f);
    return *reinterpret_cast<u16*>(&h);
}

// ---- async global->LDS, width 16B per lane, dest = wave base + lane*16 ----
__device__ __forceinline__ void gload_lds16(const void* g, void* l) {
    __builtin_amdgcn_global_load_lds(
        (const __attribute__((address_space(1))) unsigned int*)g,
        (__attribute__((address_space(3))) unsigned int*)l, 16, 0, 0);
}

// =====================================================================
// Bitmask + init of the per-layer f2-max atomic slots
__global__ __launch_bounds__(256) void k_mask(const float* __restrict__ adj,
                                              unsigned* __restrict__ mask,
                                              int* __restrict__ slots) {
    int w = blockIdx.x * 256 + threadIdx.x;
    const float4* q = (const float4*)(adj + (size_t)w * 32);
    unsigned bits = 0u;
#pragma unroll
    for (int i = 0; i < 8; i++) {
        float4 v = q[i];
        if (v.x > 0.f) bits |= (1u << (i * 4 + 0));
        if (v.y > 0.f) bits |= (1u << (i * 4 + 1));
        if (v.z > 0.f) bits |= (1u << (i * 4 + 2));
        if (v.w > 0.f) bits |= (1u << (i * 4 + 3));
    }
    mask[w] = bits;
    if (blockIdx.x == 0 && threadIdx.x < 64) slots[threadIdx.x] = (int)0x80000000;
}

// =====================================================================
__global__ void k_trans(const float* __restrict__ in, u16* __restrict__ out, int K) {
    __shared__ float t[32][33];
    const float* src = in + (size_t)blockIdx.z * K * 128;
    u16* dst = out + (size_t)blockIdx.z * K * 128;
    int k0 = blockIdx.x * 32, n0 = blockIdx.y * 32;
    int tx = threadIdx.x, ty = threadIdx.y;
#pragma unroll
    for (int i = 0; i < 32; i += 8) t[ty + i][tx] = src[(size_t)(k0 + ty + i) * 128 + n0 + tx];
    __syncthreads();
#pragma unroll
    for (int i = 0; i < 32; i += 8) dst[(size_t)(n0 + ty + i) * K + k0 + tx] = f2bf(t[tx][ty + i]);
}

// =====================================================================
__global__ __launch_bounds__(256) void k_cvt(const float* __restrict__ in,
                                             u16* __restrict__ out) {
    int t = blockIdx.x * 256 + threadIdx.x;
    float4 v = ((const float4*)in)[t];
    uint2 o;
    o.x = (unsigned)f2bf(v.x) | ((unsigned)f2bf(v.y) << 16);
    o.y = (unsigned)f2bf(v.z) | ((unsigned)f2bf(v.w) << 16);
    ((uint2*)out)[t] = o;
}

// =====================================================================
// Projection. X bf16, WT bf16 [n][k]. Writes WhT[n][j] as F16, f1 fp32,
// E12 = {2^f2', 2^0.2f2'} fp32, and atomicMax of f2' into fsl[h].
__global__ __launch_bounds__(1024, 4) void k_proj(const u16* __restrict__ X,
                                                  const u16* __restrict__ WT,
                                                  const float* __restrict__ avec,
                                                  u16* __restrict__ WhT,
                                                  float* __restrict__ f1,
                                                  float* __restrict__ E12g,
                                                  int* __restrict__ fsl, int Fin) {
    __shared__ u16 As[2][64 * 32];
    __shared__ u16 Bs[2][128 * 32];
    __shared__ float fpart[4][64][2];
    const int tid = threadIdx.x;
    const int wv = tid >> 6, lane = tid & 63;
    const int rg = wv & 3, cg = wv >> 2;
    const int c = lane & 15, quad = lane >> 4;
    const int bofs = (quad ^ ((c >> 1) & 3)) * 8;
    const int h = blockIdx.y;
    const int j0 = blockIdx.x * 64;
    const u16* Wp = WT + (size_t)h * 128 * Fin;
    const int sgr = ((lane & 3) ^ ((lane >> 3) & 3)) * 8;

#define PROJ_STAGE(buf, kb)                                                              \
    do {                                                                                 \
        if (cg == 0)                                                                     \
            gload_lds16(X + (size_t)(j0 + rg * 16 + (lane >> 2)) * Fin + (kb) + sgr,     \
                        (void*)&As[buf][rg * 16 * 32]);                                  \
        else if (cg <= 2)                                                                \
            gload_lds16(Wp + (size_t)((cg - 1) * 64 + rg * 16 + (lane >> 2)) * Fin + (kb) + sgr, \
                        (void*)&Bs[buf][((cg - 1) * 64 + rg * 16) * 32]);                \
    } while (0)

    PROJ_STAGE(0, 0);
    __syncthreads();

    f32x4 acc[2];
    acc[0] = (f32x4){0.f, 0.f, 0.f, 0.f};
    acc[1] = (f32x4){0.f, 0.f, 0.f, 0.f};

    int it = 0;
    for (int kb = 0; kb < Fin; kb += 32, it++) {
        const int cur = it & 1;
        if (kb + 32 < Fin) PROJ_STAGE(cur ^ 1, kb + 32);
        bf16x8 av = *(const bf16x8*)&As[cur][(rg * 16 + c) * 32 + bofs];
#pragma unroll
        for (int e = 0; e < 2; e++) {
            bf16x8 bv = *(const bf16x8*)&Bs[cur][((cg * 2 + e) * 16 + c) * 32 + bofs];
            acc[e] = __builtin_amdgcn_mfma_f32_16x16x32_bf16(av, bv, acc[e], 0, 0, 0);
        }
        __syncthreads();
    }

    u16* Wo = WhT + (size_t)h * 128 * 4096;
    const float* ah = avec + h * 256;
    float p1[4] = {0, 0, 0, 0}, p2[4] = {0, 0, 0, 0};
#pragma unroll
    for (int e = 0; e < 2; e++) {
        const int n = (cg * 2 + e) * 16 + c;
        float a1 = ah[n];
        float a2 = ah[128 + n];
        u16 w4[4];
#pragma unroll
        for (int r = 0; r < 4; r++) {
            float v = acc[e][r];
            w4[r] = f2h(v);                      // f16 output
            p1[r] += v * a1;
            p2[r] += v * a2;
        }
        uint2 pk;
        pk.x = (unsigned)w4[0] | ((unsigned)w4[1] << 16);
        pk.y = (unsigned)w4[2] | ((unsigned)w4[3] << 16);
        *(uint2*)&Wo[(size_t)n * 4096 + j0 + rg * 16 + quad * 4] = pk;
    }
#pragma unroll
    for (int off = 1; off < 16; off <<= 1) {
#pragma unroll
        for (int r = 0; r < 4; r++) {
            p1[r] += __shfl_xor(p1[r], off);
            p2[r] += __shfl_xor(p2[r], off);
        }
    }
    if (c == 0) {
#pragma unroll
        for (int r = 0; r < 4; r++) {
            fpart[cg][rg * 16 + quad * 4 + r][0] = p1[r];
            fpart[cg][rg * 16 + quad * 4 + r][1] = p2[r];
        }
    }
    __syncthreads();
    if (tid < 64) {
        float s1 = fpart[0][tid][0] + fpart[1][tid][0] + fpart[2][tid][0] + fpart[3][tid][0];
        float s2 = fpart[0][tid][1] + fpart[1][tid][1] + fpart[2][tid][1] + fpart[3][tid][1];
        f1[h * 4096 + j0 + tid] = s1;
        const float LOG2E = 1.4426950408889634f;
        float d = s2 * LOG2E;
        float* e12 = E12g + h * 8192 + 2 * (j0 + tid);
        e12[0] = __builtin_amdgcn_exp2f(d);
        e12[1] = __builtin_amdgcn_exp2f(0.2f * d);
        float dm = d;
#pragma unroll
        for (int off = 1; off < 64; off <<= 1) dm = fmaxf(dm, __shfl_xor(dm, off));
        if (tid == 0) {
            int b = __float_as_int(dm);
            atomicMax(fsl + h, b >= 0 ? b : (b ^ 0x7fffffff));
        }
    }
}

// =====================================================================
// Fused masked softmax attention + ELU — r6 machinery, spill-free split.
// 1024 thr = 16 waves = 4 jg (1024-j chunks) x 2 rg (row halves) x 2 ng
// (n halves). Wave: 2 row-frags x 4 n-tiles -> acc = 32 VGPRs (r6 had 64
// and spilled 165 MB/dispatch). Each Bs elem read by 2 waves (amp 2, still
// 2x better than r0). ones-MFMA on ng=0 only (ng=1 would duplicate it).
// LDS 81 KB: Bs 4x2x8KB dbuf + EL 16KB + lpart 1KB; reduce via 2 Q-buffers.
template <bool F32OUT>
__global__ __launch_bounds__(1024, 4) void k_attn(const u16* __restrict__ WhT,
                                                  const float* __restrict__ f1g,
                                                  const float* __restrict__ E12g,
                                                  const unsigned char* __restrict__ maskb,
                                                  const int* __restrict__ fmx,
                                                  void* __restrict__ outp, int ostride) {
    __shared__ uint4 SMv[5184];            // 82944 B
    char* SM = (char*)SMv;
    u16* Bsb = (u16*)SM;                   // 64 KB: [4 jg][2 buf][128n*32j] f16
    unsigned* EL = (unsigned*)(SM + 65536);  // 16 KB packed f16x2 {E1,E2} per j
    float* lpart = (float*)(SM + 81920);   // [4 jg][64 rows]

    const int tid = threadIdx.x;
    const int wv = tid >> 6, lane = tid & 63;
    const int jg = wv >> 2, rg = (wv >> 1) & 1, ng = wv & 1;
    const int sub = rg * 2 + ng;                           // staging quarter
    const int c = lane & 15, quad = lane >> 4;
    const int bofs = (quad ^ ((c >> 1) & 3)) * 8;          // swizzled read granule
    const int sgr = ((lane & 3) ^ ((lane >> 3) & 3)) * 8;  // swizzled source granule
    const int h = blockIdx.y;
    const int i0 = blockIdx.x * 64;
    const float LOG2E = 1.4426950408889634f;
    const u16* Wp = WhT + (size_t)h * 128 * 4096;

    u16* tile0 = Bsb + (jg * 2 + 0) * 4096;
    u16* tile1 = Bsb + (jg * 2 + 1) * 4096;

    // tile [128 n][32 j] staged by the 4 waves of this jg: 2 gloads each
#define ATTN_STAGE(tbuf, kb)                                                             \
    do {                                                                                 \
        const int jb_ = jg * 1024 + (kb) * 32;                                           \
        _Pragma("unroll")                                                                \
        for (int e_ = 0; e_ < 2; e_++)                                                   \
            gload_lds16(Wp + (size_t)(sub * 32 + e_ * 16 + (lane >> 2)) * 4096 + jb_ + sgr, \
                        (void*)((tbuf) + (sub * 32 + e_ * 16) * 32));                    \
    } while (0)

    ATTN_STAGE(tile0, 0);

    // ---- F2MAX + EL fill (4 j per thread) ----
    int fk = fmx[h];
    float F2MAX = __int_as_float(fk >= 0 ? fk : (fk ^ 0x7fffffff));
    float t1 = __builtin_amdgcn_exp2f(-F2MAX);
    float t2 = __builtin_amdgcn_exp2f(-0.2f * F2MAX);
    {
        int j = tid * 4;
        const float4* eg = (const float4*)(E12g + h * 8192 + 2 * j);
        float4 v0 = eg[0], v1 = eg[1];
        __half2 a0 = __floats2half2_rn(v0.x * t1, v0.y * t2);
        __half2 a1 = __floats2half2_rn(v0.z * t1, v0.w * t2);
        __half2 a2 = __floats2half2_rn(v1.x * t1, v1.y * t2);
        __half2 a3 = __floats2half2_rn(v1.z * t1, v1.w * t2);
        uint4 pk;
        pk.x = *(unsigned*)&a0; pk.y = *(unsigned*)&a1;
        pk.z = *(unsigned*)&a2; pk.w = *(unsigned*)&a3;
        *(uint4*)&EL[j] = pk;
    }

    // ---- per-frag constants {C1,C2} f16x2 (rows rg*32+c, rg*32+16+c) ----
    __half2 cpa, cpb;
    {
        float rf1 = f1g[h * 4096 + i0 + rg * 32 + c] * LOG2E;
        float zb = rf1 + F2MAX, rm = fmaxf(zb, 0.2f * zb);
        cpa = __floats2half2_rn(__builtin_amdgcn_exp2f(zb - rm),
                                __builtin_amdgcn_exp2f(0.2f * zb - rm));
    }
    {
        float rf1 = f1g[h * 4096 + i0 + rg * 32 + 16 + c] * LOG2E;
        float zb = rf1 + F2MAX, rm = fmaxf(zb, 0.2f * zb);
        cpb = __floats2half2_rn(__builtin_amdgcn_exp2f(zb - rm),
                                __builtin_amdgcn_exp2f(0.2f * zb - rm));
    }

    // mask row bases (128-byte span per row over this jg's 1024 j)
    const unsigned char* mpa = maskb + (size_t)(i0 + rg * 32 + c) * 512 + jg * 128;
    const unsigned char* mpb = mpa + 16 * 512;

    half8 ones;
#pragma unroll
    for (int i = 0; i < 8; i++) ones[i] = (_Float16)1.0f;

    f32x4 accA[4], accB[4];
#pragma unroll
    for (int i = 0; i < 4; i++) {
        accA[i] = (f32x4){0.f, 0.f, 0.f, 0.f};
        accB[i] = (f32x4){0.f, 0.f, 0.f, 0.f};
    }
    f32x4 alA = (f32x4){0.f, 0.f, 0.f, 0.f};
    f32x4 alB = (f32x4){0.f, 0.f, 0.f, 0.f};

    union AF { half8 v; unsigned u[4]; };

#define COMPF(dst, mbv, cpf)                                                             \
    do {                                                                                 \
        _Pragma("unroll")                                                                \
        for (int t = 0; t < 4; t++) {                                                    \
            __half2 e0 = *(const __half2*)&ed[2 * t];                                    \
            __half2 e1 = *(const __half2*)&ed[2 * t + 1];                                \
            __half2 pr0 = __hmul2(e0, (cpf));                                            \
            __half2 pr1 = __hmul2(e1, (cpf));                                            \
            __half m0 = __hmax(__low2half(pr0), __high2half(pr0));                       \
            __half m1 = __hmax(__low2half(pr1), __high2half(pr1));                       \
            __half2 pk2 = __halves2half2(m0, m1);                                        \
            unsigned msk = ((((mbv) >> (2 * t)) & 1u) ? 0xffffu : 0u) |                  \
                           ((((mbv) >> (2 * t + 1)) & 1u) ? 0xffff0000u : 0u);           \
            dst.u[t] = (*(const unsigned*)&pk2) & msk;                                   \
        }                                                                                \
    } while (0)

#define STEP(kb, PAR, mwa, mwb)                                                          \
    do {                                                                                 \
        u16* curb = (PAR) ? tile1 : tile0;                                               \
        if ((kb) < 31) ATTN_STAGE((PAR) ? tile0 : tile1, (kb) + 1);                      \
        uint4 ew0 = *(const uint4*)&EL[jg * 1024 + (kb) * 32 + quad * 8];                \
        uint4 ew1 = *(const uint4*)&EL[jg * 1024 + (kb) * 32 + quad * 8 + 4];            \
        const unsigned ed[8] = {ew0.x, ew0.y, ew0.z, ew0.w, ew1.x, ew1.y, ew1.z, ew1.w}; \
        const unsigned mbva = ((mwa) >> (8 * quad)) & 0xffu;                             \
        const unsigned mbvb = ((mwb) >> (8 * quad)) & 0xffu;                             \
        AF afa, afb;                                                                     \
        COMPF(afa, mbva, cpa);                                                           \
        COMPF(afb, mbvb, cpb);                                                           \
        _Pragma("unroll")                                                                \
        for (int nt = 0; nt < 4; nt++) {                                                 \
            half8 bv = *(const half8*)&curb[((ng * 64 + nt * 16) + c) * 32 + bofs];      \
            accA[nt] = __builtin_amdgcn_mfma_f32_16x16x32_f16(afa.v, bv, accA[nt], 0, 0, 0); \
            accB[nt] = __builtin_amdgcn_mfma_f32_16x16x32_f16(afb.v, bv, accB[nt], 0, 0, 0); \
        }                                                                                \
        if (ng == 0) {                                                                   \
            alA = __builtin_amdgcn_mfma_f32_16x16x32_f16(afa.v, ones, alA, 0, 0, 0);     \
            alB = __builtin_amdgcn_mfma_f32_16x16x32_f16(afb.v, ones, alB, 0, 0, 0);     \
        }                                                                                \
        __syncthreads();                                                                 \
    } while (0)

    __syncthreads();               // EL visible + tile0 staged (barrier drains vmcnt)

    for (int s = 0; s < 8; s++) {
        uint4 mca = *(const uint4*)(mpa + 16 * s);
        uint4 mcb = *(const uint4*)(mpb + 16 * s);
        STEP(s * 4 + 0, 0, mca.x, mcb.x);
        STEP(s * 4 + 1, 1, mca.y, mcb.y);
        STEP(s * 4 + 2, 0, mca.z, mcb.z);
        STEP(s * 4 + 3, 1, mca.w, mcb.w);
    }

    // ---- row denominators from ones-MFMA (ng=0 waves only) ----
    if (ng == 0 && c == 0) {
#pragma unroll
        for (int r = 0; r < 4; r++) {
            lpart[jg * 64 + rg * 32 + quad * 4 + r] = alA[r];
            lpart[jg * 64 + rg * 32 + 16 + quad * 4 + r] = alB[r];
        }
    }
    __syncthreads();               // everyone done with Bs/EL

    // ---- cross-jg reduction: 2 Q-buffers [64][132] fp32 aliased on Bs+EL ----
    float* Q = (float*)SM;         // 2 x 8448 floats = 67.6 KB < 80 KB dead
#define QIDX(f, ntv, rv) ((rg * 32 + (f) * 16 + quad * 4 + (rv)) * 132 + ng * 64 + (ntv) * 16 + c)
    if (jg >= 2) {
        float* rq = Q + (jg - 2) * 8448;
#pragma unroll
        for (int nt = 0; nt < 4; nt++)
#pragma unroll
            for (int r = 0; r < 4; r++) {
                rq[QIDX(0, nt, r)] = accA[nt][r];
                rq[QIDX(1, nt, r)] = accB[nt][r];
            }
    }
    __syncthreads();
    if (jg < 2) {
        float* rq = Q + jg * 8448;
#pragma unroll
        for (int nt = 0; nt < 4; nt++)
#pragma unroll
            for (int r = 0; r < 4; r++) {
                rq[QIDX(0, nt, r)] += accA[nt][r];
                rq[QIDX(1, nt, r)] += accB[nt][r];
            }
    }
    __syncthreads();

    // ---- epilogue: row = tid>>4 (64 rows), col-octet = tid&15 ----
    const int row = tid >> 4, cb = tid & 15;
    float l = lpart[row] + lpart[64 + row] + lpart[128 + row] + lpart[192 + row];
    const float linv = 1.0f / l;
    float vv[8];
#pragma unroll
    for (int t = 0; t < 8; t++) {
        int idx = row * 132 + cb * 8 + t;
        float v = (Q[idx] + Q[8448 + idx]) * linv;
        vv[t] = v > 0.f ? v : __expf(v) - 1.f;       // ELU
    }
    const size_t obase = (size_t)(i0 + row) * ostride + h * 128 + cb * 8;
    if (F32OUT) {
        float* op = (float*)outp + obase;
        *(float4*)op = *(float4*)&vv[0];
        *(float4*)(op + 4) = *(float4*)&vv[4];
    } else {
        uint4 o;
        o.x = (unsigned)f2bf(vv[0]) | ((unsigned)f2bf(vv[1]) << 16);
        o.y = (unsigned)f2bf(vv[2]) | ((unsigned)f2bf(vv[3]) << 16);
        o.z = (unsigned)f2bf(vv[4]) | ((unsigned)f2bf(vv[5]) << 16);
        o.w = (unsigned)f2bf(vv[6]) | ((unsigned)f2bf(vv[7]) << 16);
        *(uint4*)((u16*)outp + obase) = o;
    }
}

// =====================================================================
__global__ __launch_bounds__(256) void k_gather(const int* __restrict__ head,
                                                const int* __restrict__ rel,
                                                const float* __restrict__ ent,
                                                const float* __restrict__ rele,
                                                float* __restrict__ out) {
    int t = blockIdx.x * 256 + threadIdx.x;
    int row = t >> 5, sg = t & 31;
    int hh = head[row], rr = rel[row];
    float4 a = ((const float4*)(ent + (size_t)hh * 128))[sg];
    float4 b = ((const float4*)(rele + (size_t)rr * 128))[sg];
    float4 o;
    o.x = a.x + b.x; o.y = a.y + b.y; o.z = a.z + b.z; o.w = a.w + b.w;
    ((float4*)(out + (size_t)row * 128))[sg] = o;
}

// =====================================================================
extern "C" void kernel_launch(void* const* d_in, const int* in_sizes, int n_in,
                              void* d_out, int out_size, void* d_ws, size_t ws_size,
                              hipStream_t stream) {
    const int*   head = (const int*)d_in[0];
    const int*   rel  = (const int*)d_in[1];
    const float* adj  = (const float*)d_in[2];
    const float* ent  = (const float*)d_in[3];
    const float* rele = (const float*)d_in[4];
    const float* W0   = (const float*)d_in[5];
    const float* a0   = (const float*)d_in[6];
    const float* Wm   = (const float*)d_in[7];
    const float* am   = (const float*)d_in[8];
    const float* Wo   = (const float*)d_in[9];
    const float* ao   = (const float*)d_in[10];

    char* ws = (char*)d_ws;
    unsigned* mask = (unsigned*)(ws + 0);                 // 2 MB
    u16* WT0 = (u16*)(ws + 2097152);                      // 128 KB
    u16* WT5 = (u16*)(ws + 2228224);                      // 4.625 MB
    u16* WhT = (u16*)(ws + 7077888);                      // 4 MB (f16)
    float* f1 = (float*)(ws + 11272192);                  // 64 KB
    u16* xA = (u16*)(ws + 11403264);                      // 4 MB
    u16* xB = (u16*)(ws + 15597568);                      // 4 MB
    u16* x0 = (u16*)(ws + 19791872);                      // 1 MB
    float* E12 = (float*)(ws + 20840448);                 // 128 KB
    int* slots = (int*)(ws + 20971520);                   // 44 ints

    float* out_x = (float*)d_out;
    float* out_comb = out_x + (size_t)4096 * 128;

    k_mask<<<2048, 256, 0, stream>>>(adj, mask, slots);
    k_cvt<<<512, 256, 0, stream>>>(ent, x0);
    k_trans<<<dim3(4, 4, 4), dim3(32, 8), 0, stream>>>(W0, WT0, 128);
    k_trans<<<dim3(16, 4, 36), dim3(32, 8), 0, stream>>>(Wm, WT5, 512);
    k_trans<<<dim3(16, 4, 1), dim3(32, 8), 0, stream>>>(Wo, WT5 + (size_t)36 * 512 * 128, 512);
    k_gather<<<512, 256, 0, stream>>>(head, rel, ent, rele, out_comb);

    // layer 0 : D -> H*D   (slots 0..3)
    k_proj<<<dim3(64, 4), 1024, 0, stream>>>(x0, WT0, a0, WhT, f1, E12, slots, 128);
    k_attn<false><<<dim3(64, 4), 1024, 0, stream>>>(WhT, f1, E12, (const unsigned char*)mask,
                                                    slots, xA, 512);
    u16 *xc = xA, *xn = xB;
    // 9 middle layers : slots 4..39
    for (int l = 0; l < 9; l++) {
        k_proj<<<dim3(64, 4), 1024, 0, stream>>>(xc, WT5 + (size_t)l * 4 * 512 * 128,
                                                 am + (size_t)l * 4 * 256, WhT, f1, E12,
                                                 slots + (l + 1) * 4, 512);
        k_attn<false><<<dim3(64, 4), 1024, 0, stream>>>(WhT, f1, E12, (const unsigned char*)mask,
                                                        slots + (l + 1) * 4, xn, 512);
        u16* t = xc; xc = xn; xn = t;
    }
    // output layer : slot 40
    k_proj<<<dim3(64, 1), 1024, 0, stream>>>(xc, WT5 + (size_t)36 * 512 * 128, ao, WhT, f1, E12,
                                             slots + 40, 512);
    k_attn<true><<<dim3(64, 1), 1024, 0, stream>>>(WhT, f1, E12, (const unsigned char*)mask,
                                                   slots + 40, out_x, 128);
}

// Round 9
// 653.023 us; speedup vs baseline: 1.8951x; 1.8951x over previous
//
#include <hip/hip_runtime.h>

typedef unsigned short u16;
typedef short bf16x8 __attribute__((ext_vector_type(8)));
typedef float f32x4 __attribute__((ext_vector_type(4)));

__device__ __forceinline__ float bf2f(unsigned v) { return __uint_as_float(v << 16); }
__device__ __forceinline__ u16 f2bf(float f) {
    unsigned u = __float_as_uint(f);
    return (u16)((u + 0x7fffu + ((u >> 16) & 1u)) >> 16);
}

// ---- async global->LDS, width 16B per lane, dest = wave base + lane*16 ----
__device__ __forceinline__ void gload_lds16(const void* g, void* l) {
    __builtin_amdgcn_global_load_lds(
        (const __attribute__((address_space(1))) unsigned int*)g,
        (__attribute__((address_space(3))) unsigned int*)l, 16, 0, 0);
}

// LDS tile swizzle (both-sides): 64B rows of 4x16B granules; LDS granule
// g holds global granule g ^ ((row&15)>>1 & 3).
// Stage side: per-lane global source granule = (lane&3) ^ ((lane>>3)&3).
// Read side:  granule = quad ^ ((c>>1)&3)   (row-within-16 = c).

// =====================================================================
// Bitmask: bit j of word w  <=>  adj[w*32 + j] > 0   (adj fp32)
__global__ __launch_bounds__(256) void k_mask(const float* __restrict__ adj,
                                              unsigned* __restrict__ mask) {
    int w = blockIdx.x * 256 + threadIdx.x;           // 524288 words
    const float4* q = (const float4*)(adj + (size_t)w * 32);
    unsigned bits = 0u;
#pragma unroll
    for (int i = 0; i < 8; i++) {
        float4 v = q[i];
        if (v.x > 0.f) bits |= (1u << (i * 4 + 0));
        if (v.y > 0.f) bits |= (1u << (i * 4 + 1));
        if (v.z > 0.f) bits |= (1u << (i * 4 + 2));
        if (v.w > 0.f) bits |= (1u << (i * 4 + 3));
    }
    mask[w] = bits;
}

// =====================================================================
// Transpose [K,128] fp32 -> [128,K] bf16 per matrix (batch = blockIdx.z)
__global__ void k_trans(const float* __restrict__ in, u16* __restrict__ out, int K) {
    __shared__ float t[32][33];
    const float* src = in + (size_t)blockIdx.z * K * 128;
    u16* dst = out + (size_t)blockIdx.z * K * 128;
    int k0 = blockIdx.x * 32, n0 = blockIdx.y * 32;
    int tx = threadIdx.x, ty = threadIdx.y;           // 32 x 8
#pragma unroll
    for (int i = 0; i < 32; i += 8) t[ty + i][tx] = src[(size_t)(k0 + ty + i) * 128 + n0 + tx];
    __syncthreads();
#pragma unroll
    for (int i = 0; i < 32; i += 8) dst[(size_t)(n0 + ty + i) * K + k0 + tx] = f2bf(t[tx][ty + i]);
}

// =====================================================================
// fp32 -> bf16 elementwise (entity embedding), 4 elems/thread
__global__ __launch_bounds__(256) void k_cvt(const float* __restrict__ in,
                                             u16* __restrict__ out) {
    int t = blockIdx.x * 256 + threadIdx.x;
    float4 v = ((const float4*)in)[t];
    uint2 o;
    o.x = (unsigned)f2bf(v.x) | ((unsigned)f2bf(v.y) << 16);
    o.y = (unsigned)f2bf(v.z) | ((unsigned)f2bf(v.w) << 16);
    ((uint2*)out)[t] = o;
}

// =====================================================================
// Projection: Wh = x @ W_h  (M=4096, N=128, K=Fin). X bf16, WT bf16 [n][k],
// avec fp32. Writes WhT[n][j] bf16 and f1/f2 fp32.
// 1024 thr = 16 waves = 4 row-groups x 4 col-groups; double-buffered, one
// barrier per K-iter. LDS tiles XOR-swizzled (see top).
__global__ __launch_bounds__(1024, 4) void k_proj(const u16* __restrict__ X,
                                                  const u16* __restrict__ WT,
                                                  const float* __restrict__ avec,
                                                  u16* __restrict__ WhT,
                                                  float* __restrict__ f1,
                                                  float* __restrict__ f2, int Fin) {
    __shared__ u16 As[2][64 * 32];    // 8 KB  [row][k] (swizzled granules)
    __shared__ u16 Bs[2][128 * 32];   // 16 KB [n][k]   (swizzled granules)
    __shared__ float fpart[4][64][2]; // per-colgroup f1/f2 partials
    const int tid = threadIdx.x;
    const int wv = tid >> 6, lane = tid & 63;
    const int rg = wv & 3, cg = wv >> 2;
    const int c = lane & 15, quad = lane >> 4;
    const int bofs = (quad ^ ((c >> 1) & 3)) * 8;     // swizzled read granule
    const int h = blockIdx.y;
    const int j0 = blockIdx.x * 64;
    const u16* Wp = WT + (size_t)h * 128 * Fin;
    const int sgr = ((lane & 3) ^ ((lane >> 3) & 3)) * 8;  // swizzled source granule

    // stage: 12 of 16 waves issue one 1KB gload each (4 As rows-16, 8 Bs rows-16)
#define PROJ_STAGE(buf, kb)                                                              \
    do {                                                                                 \
        if (cg == 0)                                                                     \
            gload_lds16(X + (size_t)(j0 + rg * 16 + (lane >> 2)) * Fin + (kb) + sgr,     \
                        (void*)&As[buf][rg * 16 * 32]);                                  \
        else if (cg <= 2)                                                                \
            gload_lds16(Wp + (size_t)((cg - 1) * 64 + rg * 16 + (lane >> 2)) * Fin + (kb) + sgr, \
                        (void*)&Bs[buf][((cg - 1) * 64 + rg * 16) * 32]);                \
    } while (0)

    PROJ_STAGE(0, 0);
    __syncthreads();

    f32x4 acc[2];
    acc[0] = (f32x4){0.f, 0.f, 0.f, 0.f};
    acc[1] = (f32x4){0.f, 0.f, 0.f, 0.f};

    int it = 0;
    for (int kb = 0; kb < Fin; kb += 32, it++) {
        const int cur = it & 1;
        if (kb + 32 < Fin) PROJ_STAGE(cur ^ 1, kb + 32);
        bf16x8 av = *(const bf16x8*)&As[cur][(rg * 16 + c) * 32 + bofs];
#pragma unroll
        for (int e = 0; e < 2; e++) {
            bf16x8 bv = *(const bf16x8*)&Bs[cur][((cg * 2 + e) * 16 + c) * 32 + bofs];
            acc[e] = __builtin_amdgcn_mfma_f32_16x16x32_bf16(av, bv, acc[e], 0, 0, 0);
        }
        __syncthreads();
    }

    // epilogue: C row = rg*16+quad*4+r, col n = (cg*2+e)*16+c
    u16* Wo = WhT + (size_t)h * 128 * 4096;
    const float* ah = avec + h * 256;
    float p1[4] = {0, 0, 0, 0}, p2[4] = {0, 0, 0, 0};
#pragma unroll
    for (int e = 0; e < 2; e++) {
        const int n = (cg * 2 + e) * 16 + c;
        float a1 = ah[n];
        float a2 = ah[128 + n];
        u16 w4[4];
#pragma unroll
        for (int r = 0; r < 4; r++) {
            float v = acc[e][r];
            w4[r] = f2bf(v);
            p1[r] += v * a1;
            p2[r] += v * a2;
        }
        uint2 pk;
        pk.x = (unsigned)w4[0] | ((unsigned)w4[1] << 16);
        pk.y = (unsigned)w4[2] | ((unsigned)w4[3] << 16);
        *(uint2*)&Wo[(size_t)n * 4096 + j0 + rg * 16 + quad * 4] = pk;
    }
#pragma unroll
    for (int off = 1; off < 16; off <<= 1) {
#pragma unroll
        for (int r = 0; r < 4; r++) {
            p1[r] += __shfl_xor(p1[r], off);
            p2[r] += __shfl_xor(p2[r], off);
        }
    }
    if (c == 0) {
#pragma unroll
        for (int r = 0; r < 4; r++) {
            fpart[cg][rg * 16 + quad * 4 + r][0] = p1[r];
            fpart[cg][rg * 16 + quad * 4 + r][1] = p2[r];
        }
    }
    __syncthreads();
    if (tid < 64) {
        float s1 = fpart[0][tid][0] + fpart[1][tid][0] + fpart[2][tid][0] + fpart[3][tid][0];
        float s2 = fpart[0][tid][1] + fpart[1][tid][1] + fpart[2][tid][1] + fpart[3][tid][1];
        f1[h * 4096 + j0 + tid] = s1;
        f2[h * 4096 + j0 + tid] = s2;
    }
}

// =====================================================================
// Fused masked softmax attention + ELU — EXACT round-0 42.7 us structure
// (1024 thr = 16 waves = 4 row-groups x 4 j-groups, f2s/ms in LDS, fp32
// exp2 softmax, lsum + shfl denominators, double-buffered Bs, ONE barrier
// per K-iter) with ONE change: Bs granule XOR-swizzle (stage-side
// pre-swizzled global source + swizzled read), killing the 4.45M/dispatch
// bank-conflict cycles measured on r0.
template <bool F32OUT>
__global__ __launch_bounds__(1024, 4) void k_attn(const u16* __restrict__ WhT,
                                                  const float* __restrict__ f1g,
                                                  const float* __restrict__ f2g,
                                                  const unsigned char* __restrict__ maskb,
                                                  void* __restrict__ outp, int ostride) {
    __shared__ float f2s[4096];            // 16 KB (scaled by log2e)
    __shared__ unsigned char ms[64 * 528]; // 33 KB padded mask rows
    __shared__ u16 Bs[2][4][128 * 32];     // 64 KB double-buffered WhT tiles
    __shared__ float f1s[64];
    __shared__ float lpart[4][64];         // per-jgroup row denominators
    __shared__ float redmax[16];
    __shared__ float red[64 * 132];        // 33 KB fp32 acc reduce [i][n], pad 4

    const int tid = threadIdx.x;
    const int wv = tid >> 6, lane = tid & 63;
    const int jg = wv >> 2, rg = wv & 3;
    const int c = lane & 15, quad = lane >> 4;
    const int bofs = (quad ^ ((c >> 1) & 3)) * 8;          // swizzled read granule
    const int sgr = ((lane & 3) ^ ((lane >> 3) & 3)) * 8;  // swizzled source granule
    const int h = blockIdx.y;
    const int i0 = blockIdx.x * 64;
    const float LOG2E = 1.4426950408889634f;
    const float* f1h = f1g + h * 4096;
    const float* f2h = f2g + h * 4096;
    const u16* Wp = WhT + (size_t)h * 128 * 4096;

#define ATTN_STAGE(buf, kb)                                                              \
    do {                                                                                 \
        const int jb_ = jg * 1024 + (kb) * 32;                                           \
        _Pragma("unroll")                                                                \
        for (int e = 0; e < 2; e++)                                                      \
            gload_lds16(Wp + (size_t)(rg * 32 + e * 16 + (lane >> 2)) * 4096 + jb_ + sgr, \
                        (void*)&Bs[buf][jg][(rg * 32 + e * 16) * 32]);                   \
    } while (0)

    // stage f2 (scaled), f1 (scaled), mask; issue first Bs tile; block max f2'
    float mymax = -3.0e38f;
    {
        float4 v = ((const float4*)f2h)[tid];
        v.x *= LOG2E; v.y *= LOG2E; v.z *= LOG2E; v.w *= LOG2E;
        ((float4*)f2s)[tid] = v;
        mymax = fmaxf(fmaxf(v.x, v.y), fmaxf(v.z, v.w));
    }
    if (tid < 64) f1s[tid] = f1h[i0 + tid] * LOG2E;
    {   // 64 rows x 512 B of mask = 2048 uint4
        const uint4* msrc = (const uint4*)(maskb + (size_t)i0 * 512);
#pragma unroll
        for (int e = 0; e < 2; e++) {
            int o = tid + e * 1024;
            uint4 v = msrc[o];
            int row = o >> 5, col = o & 31;
            *(uint4*)&ms[row * 528 + col * 16] = v;
        }
    }
    ATTN_STAGE(0, 0);
#pragma unroll
    for (int off = 1; off < 64; off <<= 1) mymax = fmaxf(mymax, __shfl_xor(mymax, off));
    if (lane == 0) redmax[wv] = mymax;
    __syncthreads();
    float F2MAX = redmax[0];
#pragma unroll
    for (int i = 1; i < 16; i++) F2MAX = fmaxf(F2MAX, redmax[i]);

    const int iloc = rg * 16 + c;                    // A-fragment row (m = lane&15)
    const float rf1 = f1s[iloc];
    const float zb = rf1 + F2MAX;
    const float rm = fmaxf(zb, 0.2f * zb);           // log2-domain upper bound
    const float Ac = rf1 - rm;                       // s = max(Ac+f2', fma(.2,f2',Bc))
    const float Bc = 0.2f * rf1 - rm;

    f32x4 acc[8];
#pragma unroll
    for (int i = 0; i < 8; i++) acc[i] = (f32x4){0.f, 0.f, 0.f, 0.f};
    float lsum = 0.f;

    for (int kb = 0; kb < 32; kb++) {
        const int cur = kb & 1;
        if (kb < 31) ATTN_STAGE(cur ^ 1, kb + 1);
        const int jb = jg * 1024 + kb * 32;
        const unsigned mb = ms[iloc * 528 + jg * 128 + kb * 4 + quad];
        const float4 fa = *(const float4*)&f2s[jb + quad * 8];
        const float4 fb = *(const float4*)&f2s[jb + quad * 8 + 4];
        const float f2v[8] = {fa.x, fa.y, fa.z, fa.w, fb.x, fb.y, fb.z, fb.w};
        union { bf16x8 v; unsigned u[4]; } af;
#pragma unroll
        for (int t = 0; t < 8; t += 2) {
            float s0 = fmaxf(Ac + f2v[t],     __builtin_fmaf(0.2f, f2v[t],     Bc));
            float s1 = fmaxf(Ac + f2v[t + 1], __builtin_fmaf(0.2f, f2v[t + 1], Bc));
            float p0 = __builtin_amdgcn_exp2f(s0);
            float p1 = __builtin_amdgcn_exp2f(s1);
            // truncate to bf16 (keeps softmax exactly normalized: lsum uses the
            // same truncated values the MFMA consumes)
            unsigned u0 = ((mb >> t) & 1u)       ? (__float_as_uint(p0) & 0xffff0000u) : 0u;
            unsigned u1 = ((mb >> (t + 1)) & 1u) ? (__float_as_uint(p1) & 0xffff0000u) : 0u;
            lsum += __uint_as_float(u0) + __uint_as_float(u1);
            af.u[t >> 1] = (u0 >> 16) | u1;
        }
#pragma unroll
        for (int nt = 0; nt < 8; nt++) {
            bf16x8 bv = *(const bf16x8*)&Bs[cur][jg][(nt * 16 + c) * 32 + bofs];
            acc[nt] = __builtin_amdgcn_mfma_f32_16x16x32_bf16(af.v, bv, acc[nt], 0, 0, 0);
        }
        __syncthreads();
    }

    // per-jgroup row denominator: sum over the 4 quads
    lsum += __shfl_xor(lsum, 16);
    lsum += __shfl_xor(lsum, 32);
    if (quad == 0) lpart[jg][iloc] = lsum;

    // reduce acc across j-groups into red[i][n] (i local, stride 132)
#pragma unroll
    for (int g = 0; g < 4; g++) {
        __syncthreads();
        if (jg == g) {
#pragma unroll
            for (int nt = 0; nt < 8; nt++) {
#pragma unroll
                for (int r = 0; r < 4; r++) {
                    int idx = (rg * 16 + quad * 4 + r) * 132 + nt * 16 + c;
                    if (g == 0) red[idx] = acc[nt][r];
                    else        red[idx] += acc[nt][r];
                }
            }
        }
    }
    __syncthreads();

    // epilogue: thread -> (row = tid>>4, col-octet = tid&15)
    const int row = tid >> 4, cb = tid & 15;
    const float l = lpart[0][row] + lpart[1][row] + lpart[2][row] + lpart[3][row];
    const float linv = 1.0f / l;
    float vv[8];
#pragma unroll
    for (int t = 0; t < 8; t++) {
        float v = red[row * 132 + cb * 8 + t] * linv;
        vv[t] = v > 0.f ? v : __expf(v) - 1.f;       // ELU
    }
    const size_t obase = (size_t)(i0 + row) * ostride + h * 128 + cb * 8;
    if (F32OUT) {
        float* op = (float*)outp + obase;
        *(float4*)op = *(float4*)&vv[0];
        *(float4*)(op + 4) = *(float4*)&vv[4];
    } else {
        uint4 o;
        o.x = (unsigned)f2bf(vv[0]) | ((unsigned)f2bf(vv[1]) << 16);
        o.y = (unsigned)f2bf(vv[2]) | ((unsigned)f2bf(vv[3]) << 16);
        o.z = (unsigned)f2bf(vv[4]) | ((unsigned)f2bf(vv[5]) << 16);
        o.w = (unsigned)f2bf(vv[6]) | ((unsigned)f2bf(vv[7]) << 16);
        *(uint4*)((u16*)outp + obase) = o;
    }
}

// =====================================================================
// head_relation_combined = entity_emb[head] + relation_emb[relation] (fp32)
__global__ __launch_bounds__(256) void k_gather(const int* __restrict__ head,
                                                const int* __restrict__ rel,
                                                const float* __restrict__ ent,
                                                const float* __restrict__ rele,
                                                float* __restrict__ out) {
    int t = blockIdx.x * 256 + threadIdx.x;   // 131072 threads: row*32 + seg
    int row = t >> 5, sg = t & 31;
    int hh = head[row], rr = rel[row];
    float4 a = ((const float4*)(ent + (size_t)hh * 128))[sg];
    float4 b = ((const float4*)(rele + (size_t)rr * 128))[sg];
    float4 o;
    o.x = a.x + b.x; o.y = a.y + b.y; o.z = a.z + b.z; o.w = a.w + b.w;
    ((float4*)(out + (size_t)row * 128))[sg] = o;
}

// =====================================================================
extern "C" void kernel_launch(void* const* d_in, const int* in_sizes, int n_in,
                              void* d_out, int out_size, void* d_ws, size_t ws_size,
                              hipStream_t stream) {
    const int*   head = (const int*)d_in[0];
    const int*   rel  = (const int*)d_in[1];
    const float* adj  = (const float*)d_in[2];
    const float* ent  = (const float*)d_in[3];
    const float* rele = (const float*)d_in[4];
    const float* W0   = (const float*)d_in[5];
    const float* a0   = (const float*)d_in[6];
    const float* Wm   = (const float*)d_in[7];
    const float* am   = (const float*)d_in[8];
    const float* Wo   = (const float*)d_in[9];
    const float* ao   = (const float*)d_in[10];

    char* ws = (char*)d_ws;
    unsigned* mask = (unsigned*)(ws + 0);                 // 2 MB
    u16* WT0 = (u16*)(ws + 2097152);                      // 128 KB
    u16* WT5 = (u16*)(ws + 2228224);                      // 37 * 128 KB = 4.625 MB
    u16* WhT = (u16*)(ws + 7077888);                      // 4 MB
    float* f1 = (float*)(ws + 11272192);                  // 64 KB
    float* f2 = (float*)(ws + 11337728);                  // 64 KB
    u16* xA = (u16*)(ws + 11403264);                      // 4 MB
    u16* xB = (u16*)(ws + 15597568);                      // 4 MB
    u16* x0 = (u16*)(ws + 19791872);                      // 1 MB   (total ~20 MB)

    float* out_x = (float*)d_out;
    float* out_comb = out_x + (size_t)4096 * 128;

    k_mask<<<2048, 256, 0, stream>>>(adj, mask);
    k_cvt<<<512, 256, 0, stream>>>(ent, x0);
    k_trans<<<dim3(4, 4, 4), dim3(32, 8), 0, stream>>>(W0, WT0, 128);
    k_trans<<<dim3(16, 4, 36), dim3(32, 8), 0, stream>>>(Wm, WT5, 512);
    k_trans<<<dim3(16, 4, 1), dim3(32, 8), 0, stream>>>(Wo, WT5 + (size_t)36 * 512 * 128, 512);
    k_gather<<<512, 256, 0, stream>>>(head, rel, ent, rele, out_comb);

    // layer 0 : D -> H*D
    k_proj<<<dim3(64, 4), 1024, 0, stream>>>(x0, WT0, a0, WhT, f1, f2, 128);
    k_attn<false><<<dim3(64, 4), 1024, 0, stream>>>(WhT, f1, f2, (const unsigned char*)mask, xA, 512);
    u16 *xc = xA, *xn = xB;
    // 9 middle layers : H*D -> H*D
    for (int l = 0; l < 9; l++) {
        k_proj<<<dim3(64, 4), 1024, 0, stream>>>(xc, WT5 + (size_t)l * 4 * 512 * 128,
                                                 am + (size_t)l * 4 * 256, WhT, f1, f2, 512);
        k_attn<false><<<dim3(64, 4), 1024, 0, stream>>>(WhT, f1, f2, (const unsigned char*)mask, xn, 512);
        u16* t = xc; xc = xn; xn = t;
    }
    // output layer : H*D -> D, single head, fp32 out
    k_proj<<<dim3(64, 1), 1024, 0, stream>>>(xc, WT5 + (size_t)36 * 512 * 128, ao, WhT, f1, f2, 512);
    k_attn<true><<<dim3(64, 1), 1024, 0, stream>>>(WhT, f1, f2, (const unsigned char*)mask, out_x, 128);
}